// Round 1
// baseline (175.812 us; speedup 1.0000x reference)
//
#include <hip/hip_runtime.h>
#include <stdint.h>

typedef unsigned short u16;
typedef unsigned int u32;
typedef __attribute__((ext_vector_type(8))) short short8;
typedef __attribute__((ext_vector_type(4))) float floatx4;

__device__ __forceinline__ u16 f2b(float f) {
    u32 u = __builtin_bit_cast(u32, f);
    return (u16)((u + 0x7fffu + ((u >> 16) & 1u)) >> 16);
}

__device__ __forceinline__ void gld16(const void* g, void* l) {
    __builtin_amdgcn_global_load_lds(
        (const __attribute__((address_space(1))) u32*)g,
        (__attribute__((address_space(3))) u32*)l, 16, 0, 0);
}

// ---- row 2-norm recips: rnorm = 1/max(||row||,eps), srnorm = sqrt(rnorm) ----
__global__ __launch_bounds__(256) void prep_norms(
    const float* __restrict__ x, float* __restrict__ rnorm, float* __restrict__ srnorm) {
    int row = blockIdx.x;
    int t = threadIdx.x;
    float4 v = ((const float4*)(x + (long)row * 1024))[t];
    float ss = v.x * v.x + v.y * v.y + v.z * v.z + v.w * v.w;
    #pragma unroll
    for (int off = 32; off > 0; off >>= 1) ss += __shfl_down(ss, off);
    __shared__ float red[4];
    if ((t & 63) == 0) red[t >> 6] = ss;
    __syncthreads();
    if (t == 0) {
        float r = 1.0f / fmaxf(sqrtf(red[0] + red[1] + red[2] + red[3]), 1e-12f);
        rnorm[row] = r;
        srnorm[row] = sqrtf(r);
    }
}

// ---- dual-output scale+cast: dstT[c][r] = dstR[r][c] = bf16(src[r][c]*sr[r]) ----
__global__ __launch_bounds__(256) void transpose_scale_dual(
    const float* __restrict__ src, const float* __restrict__ sr,
    u16* __restrict__ dstT, u16* __restrict__ dstR, int rows, int cols) {
    __shared__ float tile[64][65];
    __shared__ float rbuf[64];
    int r0 = blockIdx.x * 64, c0 = blockIdx.y * 64;
    int t = threadIdx.x;
    if (t < 64) rbuf[t] = (sr != nullptr) ? sr[r0 + t] : 1.0f;
    __syncthreads();
    #pragma unroll
    for (int i = 0; i < 4; i++) {
        int lin = i * 256 + t;
        int rr = lin >> 4, c4 = (lin & 15) << 2;
        float4 v = *(const float4*)(src + (long)(r0 + rr) * cols + c0 + c4);
        float s = rbuf[rr];
        v.x *= s; v.y *= s; v.z *= s; v.w *= s;
        tile[rr][c4] = v.x; tile[rr][c4 + 1] = v.y; tile[rr][c4 + 2] = v.z; tile[rr][c4 + 3] = v.w;
        if (dstR != nullptr) {
            ushort4 o; o.x = f2b(v.x); o.y = f2b(v.y); o.z = f2b(v.z); o.w = f2b(v.w);
            *(ushort4*)(dstR + (long)(r0 + rr) * cols + c0 + c4) = o;
        }
    }
    __syncthreads();
    #pragma unroll
    for (int i = 0; i < 4; i++) {
        int lin = i * 256 + t;
        int cc = lin >> 4, r4 = (lin & 15) << 2;
        ushort4 o;
        o.x = f2b(tile[r4][cc]);
        o.y = f2b(tile[r4 + 1][cc]);
        o.z = f2b(tile[r4 + 2][cc]);
        o.w = f2b(tile[r4 + 3][cc]);
        *(ushort4*)(dstT + (long)(c0 + cc) * rows + r0 + r4) = o;
    }
}

// ---- reduce S split-K slabs of E fp32 each -> bf16 (plain, full coverage) ----
__global__ __launch_bounds__(256) void reduce_cast(
    const float* __restrict__ P, u16* __restrict__ D, int S, long E) {
    long i = ((long)blockIdx.x * 256 + threadIdx.x) * 4;
    float4 s = *(const float4*)(P + i);
    for (int z = 1; z < S; z++) {
        float4 v = *(const float4*)(P + z * E + i);
        s.x += v.x; s.y += v.y; s.z += v.z; s.w += v.w;
    }
    ushort4 o;
    o.x = f2b(s.x); o.y = f2b(s.y); o.z = f2b(s.z); o.w = f2b(s.w);
    *(ushort4*)(D + i) = o;
}

// ---- symmetric reduce for G (1024x1024, ldc=1024): GEMM computed only 128x128
// tiles (tm,tn) with tm<=tn (8x8 tile grid). At 64x64 granularity a tile
// (ti,tj) was computed iff (ti>>1) <= (tj>>1). kept -> direct sum; dropped ->
// sum mirrored (kept) tile coalesced, LDS-transpose, write. ----
__global__ __launch_bounds__(256) void reduce_sym64(
    const float* __restrict__ P, u16* __restrict__ D, int S, long E) {
    __shared__ float lt[64][65];
    int ti = blockIdx.x >> 4, tj = blockIdx.x & 15;
    int t = threadIdx.x;
    int r = t >> 4, c4 = (t & 15) << 2;
    int kept = ((ti >> 1) <= (tj >> 1));
    if (kept) {
        #pragma unroll
        for (int it = 0; it < 4; it++) {
            int row = 64 * ti + it * 16 + r;
            long idx = (long)row * 1024 + 64 * tj + c4;
            float4 s = *(const float4*)(P + idx);
            for (int z = 1; z < S; z++) {
                float4 v = *(const float4*)(P + (long)z * E + idx);
                s.x += v.x; s.y += v.y; s.z += v.z; s.w += v.w;
            }
            ushort4 o; o.x = f2b(s.x); o.y = f2b(s.y); o.z = f2b(s.z); o.w = f2b(s.w);
            *(ushort4*)(D + idx) = o;
        }
    } else {
        #pragma unroll
        for (int it = 0; it < 4; it++) {
            int row = it * 16 + r;  // row within mirrored source tile
            long idx = (long)(64 * tj + row) * 1024 + 64 * ti + c4;
            float4 s = *(const float4*)(P + idx);
            for (int z = 1; z < S; z++) {
                float4 v = *(const float4*)(P + (long)z * E + idx);
                s.x += v.x; s.y += v.y; s.z += v.z; s.w += v.w;
            }
            lt[row][c4] = s.x; lt[row][c4 + 1] = s.y; lt[row][c4 + 2] = s.z; lt[row][c4 + 3] = s.w;
        }
        __syncthreads();
        #pragma unroll
        for (int it = 0; it < 4; it++) {
            int dr = it * 16 + r;
            ushort4 o;
            o.x = f2b(lt[c4 + 0][dr]); o.y = f2b(lt[c4 + 1][dr]);
            o.z = f2b(lt[c4 + 2][dr]); o.w = f2b(lt[c4 + 3][dr]);
            *(ushort4*)(D + (long)(64 * ti + dr) * 1024 + 64 * tj + c4) = o;
        }
    }
}

// ---- GEMM: C[m][n] (per z-slab) = rs[m] * sum_k A[m][k]*B[n][k] ----
// A:[M][K] rm bf16, B:[N][K] rm bf16. Tile 128(M) x 128(N), BK=64, 256 threads
// (4 waves as 2x2 of 64x64 wave-tiles, 4x4 16x16x32 fragments each).
// m97 geometry: 2 MFMA per ds_read_b128 (MFMA-bound inner loop), XOR-swizzled
// LDS via pre-swizzled global source + linear global_load_lds dest.
// sym=1: grid.x=36 upper-triangular tiles (tm<=tn) of an 8x8 tile grid.
__global__ __launch_bounds__(256) void gemm128(
    const u16* __restrict__ A, const u16* __restrict__ B,
    float* __restrict__ C, const float* __restrict__ rowscale,
    int lda, int ldb, int ldc, int tilesN, int kIters, long coffz, int sym) {
    __shared__ __align__(16) u16 As[128 * 64];   // 16 KB
    __shared__ __align__(16) u16 Bs[128 * 64];   // 16 KB
    int tm, tn;
    if (sym) {
        int id = blockIdx.x, j = 0;
        while (true) {
            int c = j + 1;
            if (id < c) break;
            id -= c; j++;
        }
        tn = j; tm = id;   // tm <= tn
    } else {
        tm = blockIdx.x / tilesN; tn = blockIdx.x % tilesN;
    }
    long kOff = (long)blockIdx.y * kIters * 64;
    const u16* Ap = A + (long)tm * 128 * lda + kOff;
    const u16* Bp = B + (long)tn * 128 * ldb + kOff;
    long coff = (long)blockIdx.y * coffz;

    int t = threadIdx.x;
    int lane = t & 63, w = t >> 6;
    int wm = (w & 1) * 64, wn = (w >> 1) * 64;
    int r16 = lane & 15, q = lane >> 4;

    // staging chunk ids: 128 rows x 8 groups of 16B = 1024 chunks / 256 thr = 4 each
    int cl4[4];
    #pragma unroll
    for (int j = 0; j < 4; j++) cl4[j] = j * 256 + t;

    floatx4 acc[4][4];
    #pragma unroll
    for (int i = 0; i < 4; i++)
        #pragma unroll
        for (int j = 0; j < 4; j++) acc[i][j] = (floatx4){0.f, 0.f, 0.f, 0.f};

    for (int kt = 0; kt < kIters; kt++) {
        long kk = (long)kt * 64;
        #pragma unroll
        for (int j = 0; j < 4; j++) {
            int cl = cl4[j], row = cl >> 3, cg = (cl & 7) ^ (row & 7);
            gld16(Ap + (long)row * lda + kk + cg * 8, (void*)&As[cl * 8]);
        }
        #pragma unroll
        for (int j = 0; j < 4; j++) {
            int cl = cl4[j], row = cl >> 3, cg = (cl & 7) ^ (row & 7);
            gld16(Bp + (long)row * ldb + kk + cg * 8, (void*)&Bs[cl * 8]);
        }
        __syncthreads();
        #pragma unroll
        for (int ks = 0; ks < 2; ks++) {
            short8 a[4], b[4];
            #pragma unroll
            for (int i = 0; i < 4; i++) {
                int rr = wm + i * 16 + r16;
                int cc = (ks * 4 + q) ^ (rr & 7);
                a[i] = *(const short8*)&As[rr * 64 + cc * 8];
            }
            #pragma unroll
            for (int j = 0; j < 4; j++) {
                int rr = wn + j * 16 + r16;
                int cc = (ks * 4 + q) ^ (rr & 7);
                b[j] = *(const short8*)&Bs[rr * 64 + cc * 8];
            }
            #pragma unroll
            for (int i = 0; i < 4; i++)
                #pragma unroll
                for (int j = 0; j < 4; j++)
                    acc[i][j] = __builtin_amdgcn_mfma_f32_16x16x32_bf16(a[i], b[j], acc[i][j], 0, 0, 0);
        }
        __syncthreads();
    }

    int m0 = tm * 128 + wm, n0 = tn * 128 + wn;
    #pragma unroll
    for (int i = 0; i < 4; i++) {
        int mm = m0 + i * 16 + q * 4;
        float rs[4];
        #pragma unroll
        for (int r = 0; r < 4; r++) rs[r] = (rowscale != nullptr) ? rowscale[mm + r] : 1.0f;
        #pragma unroll
        for (int j = 0; j < 4; j++) {
            int nn = n0 + j * 16 + r16;
            #pragma unroll
            for (int r = 0; r < 4; r++)
                C[coff + (long)(mm + r) * ldc + nn] = acc[i][j][r] * rs[r];
        }
    }
}

extern "C" void kernel_launch(void* const* d_in, const int* in_sizes, int n_in,
                              void* d_out, int out_size, void* d_ws, size_t ws_size,
                              hipStream_t stream) {
    const float* x = (const float*)d_in[0];
    const float* wgt = (const float*)d_in[1];
    float* out = (float*)d_out;
    char* ws = (char*)d_ws;

    const size_t MB = 1048576;
    float* rnorm  = (float*)ws;                       // 32 KB
    float* srnorm = (float*)(ws + 32768);             // 32 KB
    u16*   YT     = (u16*)(ws + 65536);               // 16 MB  Y^T = (diag(sqrt r)x)^T [1024][8192]
    u16*   Yb     = (u16*)(ws + 65536 + 16 * MB);     // 16 MB  Y row-major [8192][1024]
    u16*   Wt     = (u16*)(ws + 65536 + 32 * MB);     //  2 MB  W^T bf16
    u16*   Gb     = (u16*)(ws + 65536 + 34 * MB);     //  2 MB  G bf16
    u16*   Mt     = (u16*)(ws + 65536 + 36 * MB);     //  2 MB  M^T bf16
    float* Gp     = (float*)(ws + 65536 + 38 * MB);   // 32 MB  8x4MB G partials
    float* Mp     = (float*)(ws + 65536 + 70 * MB);   //  8 MB  2x4MB M^T partials
    // total ~78 MB

    // 1) row norms
    prep_norms<<<8192, 256, 0, stream>>>(x, rnorm, srnorm);
    // 2) Y in both layouts from one read of x
    transpose_scale_dual<<<dim3(128, 16), 256, 0, stream>>>(x, srnorm, YT, Yb, 8192, 1024);
    // 3) Wt = W^T bf16
    transpose_scale_dual<<<dim3(16, 16), 256, 0, stream>>>(wgt, nullptr, Wt, nullptr, 1024, 1024);
    // 4) G = Y^T·Y, upper-tri 128x128 tiles only (36 of 64), split-K=8 -> Gp
    gemm128<<<dim3(36, 8), 256, 0, stream>>>(YT, YT, Gp, nullptr,
                                             8192, 8192, 1024, 8, 16, 1048576, 1);
    // 5) Gb = bf16(sum Gp), mirroring the lower triangle
    reduce_sym64<<<256, 256, 0, stream>>>(Gp, Gb, 8, 1048576);
    // 6) M^T = W^T·G (G symmetric), split-K=2 -> Mp
    gemm128<<<dim3(64, 2), 256, 0, stream>>>(Wt, Gb, Mp, nullptr,
                                             1024, 1024, 1024, 8, 8, 1048576, 0);
    // 7) Mt = bf16(sum Mp)
    reduce_cast<<<1024, 256, 0, stream>>>(Mp, Mt, 2, 1048576);
    // 8) out = diag(sqrt r)·Y·M  (M=8192, N=1024, K=1024, 512 blocks)
    gemm128<<<dim3(512, 1), 256, 0, stream>>>(Yb, Mt, out, srnorm,
                                              1024, 1024, 1024, 8, 16, 0, 0);
}

// Round 2
// 170.645 us; speedup vs baseline: 1.0303x; 1.0303x over previous
//
#include <hip/hip_runtime.h>
#include <stdint.h>

typedef unsigned short u16;
typedef unsigned int u32;
typedef __attribute__((ext_vector_type(8))) short short8;
typedef __attribute__((ext_vector_type(4))) float floatx4;

__device__ __forceinline__ u16 f2b(float f) {
    u32 u = __builtin_bit_cast(u32, f);
    return (u16)((u + 0x7fffu + ((u >> 16) & 1u)) >> 16);
}

__device__ __forceinline__ void gld16(const void* g, void* l) {
    __builtin_amdgcn_global_load_lds(
        (const __attribute__((address_space(1))) u32*)g,
        (__attribute__((address_space(3))) u32*)l, 16, 0, 0);
}

// ---- fused: row 2-norms + dual-layout scale/cast, 32 rows/block ----
// r = 1/max(||x_row||,eps). Yn[r][c] = bf16(x*r)  (row-major, stage-8 A)
//                           YT[c][r] = bf16(x*sqrt(r)) (transposed, stage-4 A/B)
__global__ __launch_bounds__(256) void fuse_prep(
    const float* __restrict__ x, u16* __restrict__ YT, u16* __restrict__ Yn) {
    __shared__ float tile[32][129];
    int r0 = blockIdx.x * 32;
    int t = threadIdx.x;
    int tg = t >> 5, tl = t & 31;
    // phase A: row sums of squares (each thread: 4 rows x 4 cols x 8 chunks)
    float ss[4] = {0.f, 0.f, 0.f, 0.f};
    for (int c = 0; c < 8; c++) {
        #pragma unroll
        for (int i = 0; i < 4; i++) {
            int rr = i * 8 + tg;
            float4 v = *(const float4*)(x + (long)(r0 + rr) * 1024 + c * 128 + tl * 4);
            ss[i] += v.x * v.x + v.y * v.y + v.z * v.z + v.w * v.w;
        }
    }
    float rs_[4], sr_[4];
    #pragma unroll
    for (int i = 0; i < 4; i++) {
        #pragma unroll
        for (int m = 16; m > 0; m >>= 1) ss[i] += __shfl_xor(ss[i], m);
        float rcp = 1.0f / fmaxf(sqrtf(ss[i]), 1e-12f);
        rs_[i] = rcp;
        sr_[i] = sqrtf(rcp);
    }
    // phase B: re-read (L2/L3-hot), scale, write Yn + transpose to YT
    for (int c = 0; c < 8; c++) {
        __syncthreads();
        #pragma unroll
        for (int i = 0; i < 4; i++) {
            int rr = i * 8 + tg;
            float4 v = *(const float4*)(x + (long)(r0 + rr) * 1024 + c * 128 + tl * 4);
            ushort4 o;
            o.x = f2b(v.x * rs_[i]); o.y = f2b(v.y * rs_[i]);
            o.z = f2b(v.z * rs_[i]); o.w = f2b(v.w * rs_[i]);
            *(ushort4*)(Yn + (long)(r0 + rr) * 1024 + c * 128 + tl * 4) = o;
            tile[rr][tl * 4 + 0] = v.x * sr_[i];
            tile[rr][tl * 4 + 1] = v.y * sr_[i];
            tile[rr][tl * 4 + 2] = v.z * sr_[i];
            tile[rr][tl * 4 + 3] = v.w * sr_[i];
        }
        __syncthreads();
        #pragma unroll
        for (int i = 0; i < 4; i++) {
            int lin = i * 256 + t;
            int cc = lin >> 3, r4 = (lin & 7) << 2;
            ushort4 o;
            o.x = f2b(tile[r4 + 0][cc]); o.y = f2b(tile[r4 + 1][cc]);
            o.z = f2b(tile[r4 + 2][cc]); o.w = f2b(tile[r4 + 3][cc]);
            *(ushort4*)(YT + (long)(c * 128 + cc) * 8192 + r0 + r4) = o;
        }
    }
}

// ---- transpose+cast (used for W only): dstT[c][r] = bf16(src[r][c]) ----
__global__ __launch_bounds__(256) void transpose_scale_dual(
    const float* __restrict__ src, const float* __restrict__ sr,
    u16* __restrict__ dstT, u16* __restrict__ dstR, int rows, int cols) {
    __shared__ float tile[64][65];
    __shared__ float rbuf[64];
    int r0 = blockIdx.x * 64, c0 = blockIdx.y * 64;
    int t = threadIdx.x;
    if (t < 64) rbuf[t] = (sr != nullptr) ? sr[r0 + t] : 1.0f;
    __syncthreads();
    #pragma unroll
    for (int i = 0; i < 4; i++) {
        int lin = i * 256 + t;
        int rr = lin >> 4, c4 = (lin & 15) << 2;
        float4 v = *(const float4*)(src + (long)(r0 + rr) * cols + c0 + c4);
        float s = rbuf[rr];
        v.x *= s; v.y *= s; v.z *= s; v.w *= s;
        tile[rr][c4] = v.x; tile[rr][c4 + 1] = v.y; tile[rr][c4 + 2] = v.z; tile[rr][c4 + 3] = v.w;
        if (dstR != nullptr) {
            ushort4 o; o.x = f2b(v.x); o.y = f2b(v.y); o.z = f2b(v.z); o.w = f2b(v.w);
            *(ushort4*)(dstR + (long)(r0 + rr) * cols + c0 + c4) = o;
        }
    }
    __syncthreads();
    #pragma unroll
    for (int i = 0; i < 4; i++) {
        int lin = i * 256 + t;
        int cc = lin >> 4, r4 = (lin & 15) << 2;
        ushort4 o;
        o.x = f2b(tile[r4][cc]);
        o.y = f2b(tile[r4 + 1][cc]);
        o.z = f2b(tile[r4 + 2][cc]);
        o.w = f2b(tile[r4 + 3][cc]);
        *(ushort4*)(dstT + (long)(c0 + cc) * rows + r0 + r4) = o;
    }
}

// ---- symmetric reduce for G (1024x1024): stage-4 computed 64x64 tiles (ti,tj)
// iff ti <= 2*(tj>>1)+1 (64x128 tiling, tm<=2*tn+1). kept -> direct sum;
// dropped -> sum mirrored tile coalesced, LDS-transpose, write. ----
__global__ __launch_bounds__(256) void reduce_sym64(
    const float* __restrict__ P, u16* __restrict__ D, int S, long E) {
    __shared__ float lt[64][65];
    int ti = blockIdx.x >> 4, tj = blockIdx.x & 15;
    int t = threadIdx.x;
    int r = t >> 4, c4 = (t & 15) << 2;
    int kept = (ti <= 2 * (tj >> 1) + 1);
    if (kept) {
        #pragma unroll
        for (int it = 0; it < 4; it++) {
            int row = 64 * ti + it * 16 + r;
            long idx = (long)row * 1024 + 64 * tj + c4;
            float4 s = *(const float4*)(P + idx);
            for (int z = 1; z < S; z++) {
                float4 v = *(const float4*)(P + (long)z * E + idx);
                s.x += v.x; s.y += v.y; s.z += v.z; s.w += v.w;
            }
            ushort4 o; o.x = f2b(s.x); o.y = f2b(s.y); o.z = f2b(s.z); o.w = f2b(s.w);
            *(ushort4*)(D + idx) = o;
        }
    } else {
        #pragma unroll
        for (int it = 0; it < 4; it++) {
            int row = it * 16 + r;  // row within mirrored source tile
            long idx = (long)(64 * tj + row) * 1024 + 64 * ti + c4;
            float4 s = *(const float4*)(P + idx);
            for (int z = 1; z < S; z++) {
                float4 v = *(const float4*)(P + (long)z * E + idx);
                s.x += v.x; s.y += v.y; s.z += v.z; s.w += v.w;
            }
            lt[row][c4] = s.x; lt[row][c4 + 1] = s.y; lt[row][c4 + 2] = s.z; lt[row][c4 + 3] = s.w;
        }
        __syncthreads();
        #pragma unroll
        for (int it = 0; it < 4; it++) {
            int dr = it * 16 + r;
            ushort4 o;
            o.x = f2b(lt[c4 + 0][dr]); o.y = f2b(lt[c4 + 1][dr]);
            o.z = f2b(lt[c4 + 2][dr]); o.w = f2b(lt[c4 + 3][dr]);
            *(ushort4*)(D + (long)(64 * ti + dr) * 1024 + 64 * tj + c4) = o;
        }
    }
}

// ---- GEMM 64(M)x128(N), BK=64, 4 waves (2x2 of 32x64): C = rs[m]*sum A[m][k]B[n][k]
// XOR-swizzled LDS, gld16 staging, 4 blocks/CU. XCD-chunked block swizzle.
// sym=1: grid.x=72 tiles (tm<=2*tn+1) of a 16x8 tile grid.
// obf16=1: write bf16 (u16) C instead of fp32. ----
__global__ __launch_bounds__(256, 4) void gemm64x128(
    const u16* __restrict__ A, const u16* __restrict__ B,
    float* __restrict__ C, const float* __restrict__ rowscale,
    int lda, int ldb, int ldc, int tilesN, int kIters, long coffz, int sym, int obf16) {
    __shared__ __align__(16) u16 As[64 * 64];    //  8 KB
    __shared__ __align__(16) u16 Bs[128 * 64];   // 16 KB
    int bid = blockIdx.x;
    int nx = gridDim.x;
    if ((nx & 7) == 0) { int cpx = nx >> 3; bid = (bid & 7) * cpx + (bid >> 3); }
    int tm, tn;
    if (sym) {
        int id = bid, j = 0;
        while (true) {
            int c = (2 * j + 2 < 16) ? (2 * j + 2) : 16;
            if (id < c) break;
            id -= c; j++;
        }
        tn = j; tm = id;
    } else {
        tm = bid / tilesN; tn = bid % tilesN;
    }
    long kOff = (long)blockIdx.y * kIters * 64;
    const u16* Ap = A + (long)tm * 64 * lda + kOff;
    const u16* Bp = B + (long)tn * 128 * ldb + kOff;
    long coff = (long)blockIdx.y * coffz;

    int t = threadIdx.x;
    int lane = t & 63, w = t >> 6;
    int wm = (w & 1) * 32, wn = (w >> 1) * 64;
    int r16 = lane & 15, q = lane >> 4;

    int acl[2], bcl[4];
    #pragma unroll
    for (int j = 0; j < 2; j++) acl[j] = (w * 2 + j) * 64 + lane;
    #pragma unroll
    for (int j = 0; j < 4; j++) bcl[j] = (w * 4 + j) * 64 + lane;

    floatx4 acc[2][4];
    #pragma unroll
    for (int i = 0; i < 2; i++)
        #pragma unroll
        for (int j = 0; j < 4; j++) acc[i][j] = (floatx4){0.f, 0.f, 0.f, 0.f};

    for (int kt = 0; kt < kIters; kt++) {
        long kk = (long)kt * 64;
        #pragma unroll
        for (int j = 0; j < 2; j++) {
            int cl = acl[j], row = cl >> 3, cg = (cl & 7) ^ (row & 7);
            gld16(Ap + (long)row * lda + kk + cg * 8, (void*)&As[cl * 8]);
        }
        #pragma unroll
        for (int j = 0; j < 4; j++) {
            int cl = bcl[j], row = cl >> 3, cg = (cl & 7) ^ (row & 7);
            gld16(Bp + (long)row * ldb + kk + cg * 8, (void*)&Bs[cl * 8]);
        }
        __syncthreads();
        #pragma unroll
        for (int ks = 0; ks < 2; ks++) {
            short8 a[2], b[4];
            #pragma unroll
            for (int i = 0; i < 2; i++) {
                int rr = wm + i * 16 + r16;
                int cc = (ks * 4 + q) ^ (rr & 7);
                a[i] = *(const short8*)&As[rr * 64 + cc * 8];
            }
            #pragma unroll
            for (int j = 0; j < 4; j++) {
                int rr = wn + j * 16 + r16;
                int cc = (ks * 4 + q) ^ (rr & 7);
                b[j] = *(const short8*)&Bs[rr * 64 + cc * 8];
            }
            #pragma unroll
            for (int i = 0; i < 2; i++)
                #pragma unroll
                for (int j = 0; j < 4; j++)
                    acc[i][j] = __builtin_amdgcn_mfma_f32_16x16x32_bf16(a[i], b[j], acc[i][j], 0, 0, 0);
        }
        __syncthreads();
    }

    int m0 = tm * 64 + wm, n0 = tn * 128 + wn;
    #pragma unroll
    for (int i = 0; i < 2; i++) {
        int mm = m0 + i * 16 + q * 4;
        float rs[4];
        #pragma unroll
        for (int r = 0; r < 4; r++) rs[r] = (rowscale != nullptr) ? rowscale[mm + r] : 1.0f;
        #pragma unroll
        for (int j = 0; j < 4; j++) {
            int nn = n0 + j * 16 + r16;
            #pragma unroll
            for (int r = 0; r < 4; r++) {
                float v = acc[i][j][r] * rs[r];
                if (obf16) ((u16*)C)[coff + (long)(mm + r) * ldc + nn] = f2b(v);
                else       C[coff + (long)(mm + r) * ldc + nn] = v;
            }
        }
    }
}

// ---- GEMM 128x128 (stage 8): m97 geometry, 2 MFMA per ds_read_b128 ----
__global__ __launch_bounds__(256) void gemm128(
    const u16* __restrict__ A, const u16* __restrict__ B,
    float* __restrict__ C, const float* __restrict__ rowscale,
    int lda, int ldb, int ldc, int tilesN, int kIters) {
    __shared__ __align__(16) u16 As[128 * 64];   // 16 KB
    __shared__ __align__(16) u16 Bs[128 * 64];   // 16 KB
    int bid = blockIdx.x;
    int nx = gridDim.x;
    if ((nx & 7) == 0) { int cpx = nx >> 3; bid = (bid & 7) * cpx + (bid >> 3); }
    int tm = bid / tilesN, tn = bid % tilesN;
    const u16* Ap = A + (long)tm * 128 * lda;
    const u16* Bp = B + (long)tn * 128 * ldb;

    int t = threadIdx.x;
    int lane = t & 63, w = t >> 6;
    int wm = (w & 1) * 64, wn = (w >> 1) * 64;
    int r16 = lane & 15, q = lane >> 4;

    floatx4 acc[4][4];
    #pragma unroll
    for (int i = 0; i < 4; i++)
        #pragma unroll
        for (int j = 0; j < 4; j++) acc[i][j] = (floatx4){0.f, 0.f, 0.f, 0.f};

    for (int kt = 0; kt < kIters; kt++) {
        long kk = (long)kt * 64;
        #pragma unroll
        for (int j = 0; j < 4; j++) {
            int cl = j * 256 + t, row = cl >> 3, cg = (cl & 7) ^ (row & 7);
            gld16(Ap + (long)row * lda + kk + cg * 8, (void*)&As[cl * 8]);
        }
        #pragma unroll
        for (int j = 0; j < 4; j++) {
            int cl = j * 256 + t, row = cl >> 3, cg = (cl & 7) ^ (row & 7);
            gld16(Bp + (long)row * ldb + kk + cg * 8, (void*)&Bs[cl * 8]);
        }
        __syncthreads();
        #pragma unroll
        for (int ks = 0; ks < 2; ks++) {
            short8 a[4], b[4];
            #pragma unroll
            for (int i = 0; i < 4; i++) {
                int rr = wm + i * 16 + r16;
                int cc = (ks * 4 + q) ^ (rr & 7);
                a[i] = *(const short8*)&As[rr * 64 + cc * 8];
            }
            #pragma unroll
            for (int j = 0; j < 4; j++) {
                int rr = wn + j * 16 + r16;
                int cc = (ks * 4 + q) ^ (rr & 7);
                b[j] = *(const short8*)&Bs[rr * 64 + cc * 8];
            }
            #pragma unroll
            for (int i = 0; i < 4; i++)
                #pragma unroll
                for (int j = 0; j < 4; j++)
                    acc[i][j] = __builtin_amdgcn_mfma_f32_16x16x32_bf16(a[i], b[j], acc[i][j], 0, 0, 0);
        }
        __syncthreads();
    }

    int m0 = tm * 128 + wm, n0 = tn * 128 + wn;
    #pragma unroll
    for (int i = 0; i < 4; i++) {
        int mm = m0 + i * 16 + q * 4;
        float rs[4];
        #pragma unroll
        for (int r = 0; r < 4; r++) rs[r] = (rowscale != nullptr) ? rowscale[mm + r] : 1.0f;
        #pragma unroll
        for (int j = 0; j < 4; j++) {
            int nn = n0 + j * 16 + r16;
            #pragma unroll
            for (int r = 0; r < 4; r++)
                C[(long)(mm + r) * ldc + nn] = acc[i][j][r] * rs[r];
        }
    }
}

extern "C" void kernel_launch(void* const* d_in, const int* in_sizes, int n_in,
                              void* d_out, int out_size, void* d_ws, size_t ws_size,
                              hipStream_t stream) {
    const float* x = (const float*)d_in[0];
    const float* wgt = (const float*)d_in[1];
    float* out = (float*)d_out;
    char* ws = (char*)d_ws;

    const size_t MB = 1048576;
    u16*   YT = (u16*)ws;                  // 16 MB  Y^T = (diag(sqrt r)x)^T [1024][8192]
    u16*   Yn = (u16*)(ws + 16 * MB);      // 16 MB  norm = diag(r)x row-major [8192][1024]
    u16*   Wt = (u16*)(ws + 32 * MB);      //  2 MB  W^T bf16
    u16*   Gb = (u16*)(ws + 34 * MB);      //  2 MB  G bf16
    u16*   Mt = (u16*)(ws + 36 * MB);      //  2 MB  M^T bf16
    float* Gp = (float*)(ws + 38 * MB);    // 32 MB  8x4MB G partials
    // total 70 MB

    // 1) fused: row norms + Y^T (sqrt-scaled) + Yn (full-scaled) from x
    fuse_prep<<<256, 256, 0, stream>>>(x, YT, Yn);
    // 2) Wt = W^T bf16
    transpose_scale_dual<<<dim3(16, 16), 256, 0, stream>>>(wgt, nullptr, Wt, nullptr, 1024, 1024);
    // 3) G = Y^T·Y, upper-tri tiles (72 of 128 in 16x8 grid), split-K=8 -> Gp
    gemm64x128<<<dim3(72, 8), 256, 0, stream>>>(YT, YT, Gp, nullptr,
                                                8192, 8192, 1024, 8, 16, 1048576, 1, 0);
    // 4) Gb = bf16(sum Gp), mirroring the lower triangle
    reduce_sym64<<<256, 256, 0, stream>>>(Gp, Gb, 8, 1048576);
    // 5) M^T = W^T·G (G symmetric), no split-K, bf16 out -> Mt
    gemm64x128<<<dim3(128, 1), 256, 0, stream>>>(Wt, Gb, (float*)Mt, nullptr,
                                                 1024, 1024, 1024, 8, 16, 0, 0, 1);
    // 6) out = norm·M  (M=8192, N=1024, K=1024, 512 blocks, no rowscale)
    gemm128<<<dim3(512, 1), 256, 0, stream>>>(Yn, Mt, out, nullptr,
                                              1024, 1024, 1024, 8, 16);
}

// Round 3
// 162.319 us; speedup vs baseline: 1.0831x; 1.0513x over previous
//
#include <hip/hip_runtime.h>
#include <stdint.h>

typedef unsigned short u16;
typedef unsigned int u32;
typedef __attribute__((ext_vector_type(8))) short short8;
typedef __attribute__((ext_vector_type(4))) float floatx4;

__device__ __forceinline__ u16 f2b(float f) {
    u32 u = __builtin_bit_cast(u32, f);
    return (u16)((u + 0x7fffu + ((u >> 16) & 1u)) >> 16);
}

__device__ __forceinline__ void gld16(const void* g, void* l) {
    __builtin_amdgcn_global_load_lds(
        (const __attribute__((address_space(1))) u32*)g,
        (__attribute__((address_space(3))) u32*)l, 16, 0, 0);
}

// ---- merged prep: blocks 0..255 = row norms + dual-layout Y; 256..511 = W^T ----
// r = 1/max(||x_row||,eps). Yn[r][c] = bf16(x*r); YT[c][r] = bf16(x*sqrt(r));
// Wt[c][r] = bf16(wgt[r][c]).
__global__ __launch_bounds__(256) void prep_all(
    const float* __restrict__ x, const float* __restrict__ wgt,
    u16* __restrict__ YT, u16* __restrict__ Yn, u16* __restrict__ Wt) {
    __shared__ __align__(16) float sh[64 * 66];
    int b = blockIdx.x;
    int t = threadIdx.x;
    if (b < 256) {
        float (*tile)[129] = (float(*)[129])sh;   // 32*129 = 4128 <= 4224
        int r0 = b * 32;
        int tg = t >> 5, tl = t & 31;
        // phase A: row sums of squares
        float ss[4] = {0.f, 0.f, 0.f, 0.f};
        for (int c = 0; c < 8; c++) {
            #pragma unroll
            for (int i = 0; i < 4; i++) {
                int rr = i * 8 + tg;
                float4 v = *(const float4*)(x + (long)(r0 + rr) * 1024 + c * 128 + tl * 4);
                ss[i] += v.x * v.x + v.y * v.y + v.z * v.z + v.w * v.w;
            }
        }
        float rs_[4], sr_[4];
        #pragma unroll
        for (int i = 0; i < 4; i++) {
            #pragma unroll
            for (int m = 16; m > 0; m >>= 1) ss[i] += __shfl_xor(ss[i], m);
            float rcp = 1.0f / fmaxf(sqrtf(ss[i]), 1e-12f);
            rs_[i] = rcp;
            sr_[i] = sqrtf(rcp);
        }
        // phase B: re-read (cache-hot), scale, write Yn + transpose to YT
        for (int c = 0; c < 8; c++) {
            __syncthreads();
            #pragma unroll
            for (int i = 0; i < 4; i++) {
                int rr = i * 8 + tg;
                float4 v = *(const float4*)(x + (long)(r0 + rr) * 1024 + c * 128 + tl * 4);
                ushort4 o;
                o.x = f2b(v.x * rs_[i]); o.y = f2b(v.y * rs_[i]);
                o.z = f2b(v.z * rs_[i]); o.w = f2b(v.w * rs_[i]);
                *(ushort4*)(Yn + (long)(r0 + rr) * 1024 + c * 128 + tl * 4) = o;
                tile[rr][tl * 4 + 0] = v.x * sr_[i];
                tile[rr][tl * 4 + 1] = v.y * sr_[i];
                tile[rr][tl * 4 + 2] = v.z * sr_[i];
                tile[rr][tl * 4 + 3] = v.w * sr_[i];
            }
            __syncthreads();
            #pragma unroll
            for (int i = 0; i < 4; i++) {
                int lin = i * 256 + t;
                int cc = lin >> 3, r4 = (lin & 7) << 2;
                ushort4 o;
                o.x = f2b(tile[r4 + 0][cc]); o.y = f2b(tile[r4 + 1][cc]);
                o.z = f2b(tile[r4 + 2][cc]); o.w = f2b(tile[r4 + 3][cc]);
                *(ushort4*)(YT + (long)(c * 128 + cc) * 8192 + r0 + r4) = o;
            }
        }
    } else {
        float (*tile)[65] = (float(*)[65])sh;     // 64*65 = 4160 <= 4224
        int bb = b - 256;
        int r0 = (bb >> 4) * 64, c0 = (bb & 15) * 64;
        #pragma unroll
        for (int i = 0; i < 4; i++) {
            int lin = i * 256 + t;
            int rr = lin >> 4, c4 = (lin & 15) << 2;
            float4 v = *(const float4*)(wgt + (long)(r0 + rr) * 1024 + c0 + c4);
            tile[rr][c4] = v.x; tile[rr][c4 + 1] = v.y;
            tile[rr][c4 + 2] = v.z; tile[rr][c4 + 3] = v.w;
        }
        __syncthreads();
        #pragma unroll
        for (int i = 0; i < 4; i++) {
            int lin = i * 256 + t;
            int cc = lin >> 4, r4 = (lin & 15) << 2;
            ushort4 o;
            o.x = f2b(tile[r4][cc]);
            o.y = f2b(tile[r4 + 1][cc]);
            o.z = f2b(tile[r4 + 2][cc]);
            o.w = f2b(tile[r4 + 3][cc]);
            *(ushort4*)(Wt + (long)(c0 + cc) * 1024 + r0 + r4) = o;
        }
    }
}

// ---- symmetric reduce for G: stage-G computed 64x64 tiles (ti,tj) iff
// ti <= 2*(tj>>1)+1. One block per KEPT tile: direct sum+write; if the
// mirror (tj,ti) was NOT computed, also write the transpose. Non-kept
// blocks exit. Reads each kept tile once (18MB vs 32MB). ----
__global__ __launch_bounds__(256) void reduce_symC(
    const float* __restrict__ P, u16* __restrict__ D, int S, long E) {
    __shared__ float lt[64][65];
    int ti = blockIdx.x >> 4, tj = blockIdx.x & 15;
    if (ti > 2 * (tj >> 1) + 1) return;               // not computed
    int mir = (tj > 2 * (ti >> 1) + 1);               // mirror not computed
    int t = threadIdx.x;
    int r = t >> 4, c4 = (t & 15) << 2;
    #pragma unroll
    for (int it = 0; it < 4; it++) {
        int row = it * 16 + r;
        long idx = (long)(64 * ti + row) * 1024 + 64 * tj + c4;
        float4 s = *(const float4*)(P + idx);
        for (int z = 1; z < S; z++) {
            float4 v = *(const float4*)(P + (long)z * E + idx);
            s.x += v.x; s.y += v.y; s.z += v.z; s.w += v.w;
        }
        ushort4 o; o.x = f2b(s.x); o.y = f2b(s.y); o.z = f2b(s.z); o.w = f2b(s.w);
        *(ushort4*)(D + idx) = o;
        if (mir) {
            lt[row][c4] = s.x; lt[row][c4 + 1] = s.y;
            lt[row][c4 + 2] = s.z; lt[row][c4 + 3] = s.w;
        }
    }
    if (mir) {
        __syncthreads();
        #pragma unroll
        for (int it = 0; it < 4; it++) {
            int dr = it * 16 + r;
            ushort4 o;
            o.x = f2b(lt[c4 + 0][dr]); o.y = f2b(lt[c4 + 1][dr]);
            o.z = f2b(lt[c4 + 2][dr]); o.w = f2b(lt[c4 + 3][dr]);
            *(ushort4*)(D + (long)(64 * tj + dr) * 1024 + 64 * ti + c4) = o;
        }
    }
}

// ---- GEMM 64(M)x128(N), BK=128: C = rs[m]*sum A[m][k]B[n][k] ----
// 4 waves (2x2 of 32x64). XOR-swizzled LDS (16 chunks/row: cg=(cl&15)^(row&15)),
// gld16 staging, 48KB LDS -> 3 blocks/CU. Halved barrier count vs BK=64.
// sym=1: grid.x=72 tiles (tm<=2*tn+1) of a 16x8 tile grid. obf16: bf16 C.
__global__ __launch_bounds__(256, 3) void gemm64x128(
    const u16* __restrict__ A, const u16* __restrict__ B,
    float* __restrict__ C, const float* __restrict__ rowscale,
    int lda, int ldb, int ldc, int tilesN, int kIters, long coffz, int sym, int obf16) {
    __shared__ __align__(16) u16 As[64 * 128];    // 16 KB
    __shared__ __align__(16) u16 Bs[128 * 128];   // 32 KB
    int bid = blockIdx.x;
    int nx = gridDim.x;
    if ((nx & 7) == 0) { int cpx = nx >> 3; bid = (bid & 7) * cpx + (bid >> 3); }
    int tm, tn;
    if (sym) {
        int id = bid, j = 0;
        while (true) {
            int c = (2 * j + 2 < 16) ? (2 * j + 2) : 16;
            if (id < c) break;
            id -= c; j++;
        }
        tn = j; tm = id;
    } else {
        tm = bid / tilesN; tn = bid % tilesN;
    }
    long kOff = (long)blockIdx.y * kIters * 128;
    const u16* Ap = A + (long)tm * 64 * lda + kOff;
    const u16* Bp = B + (long)tn * 128 * ldb + kOff;
    long coff = (long)blockIdx.y * coffz;

    int t = threadIdx.x;
    int lane = t & 63, w = t >> 6;
    int wm = (w & 1) * 32, wn = (w >> 1) * 64;
    int r16 = lane & 15, q = lane >> 4;

    floatx4 acc[2][4];
    #pragma unroll
    for (int i = 0; i < 2; i++)
        #pragma unroll
        for (int j = 0; j < 4; j++) acc[i][j] = (floatx4){0.f, 0.f, 0.f, 0.f};

    for (int kt = 0; kt < kIters; kt++) {
        long kk = (long)kt * 128;
        #pragma unroll
        for (int j = 0; j < 4; j++) {   // A: 64 rows x 16 chunks = 1024
            int cl = j * 256 + t, row = cl >> 4, cg = (cl & 15) ^ (row & 15);
            gld16(Ap + (long)row * lda + kk + cg * 8, (void*)&As[cl * 8]);
        }
        #pragma unroll
        for (int j = 0; j < 8; j++) {   // B: 128 rows x 16 chunks = 2048
            int cl = j * 256 + t, row = cl >> 4, cg = (cl & 15) ^ (row & 15);
            gld16(Bp + (long)row * ldb + kk + cg * 8, (void*)&Bs[cl * 8]);
        }
        __syncthreads();
        #pragma unroll
        for (int ks = 0; ks < 4; ks++) {
            short8 a[2], b[4];
            #pragma unroll
            for (int i = 0; i < 2; i++) {
                int rr = wm + i * 16 + r16;
                int cc = (ks * 4 + q) ^ (rr & 15);
                a[i] = *(const short8*)&As[rr * 128 + cc * 8];
            }
            #pragma unroll
            for (int j = 0; j < 4; j++) {
                int rr = wn + j * 16 + r16;
                int cc = (ks * 4 + q) ^ (rr & 15);
                b[j] = *(const short8*)&Bs[rr * 128 + cc * 8];
            }
            #pragma unroll
            for (int i = 0; i < 2; i++)
                #pragma unroll
                for (int j = 0; j < 4; j++)
                    acc[i][j] = __builtin_amdgcn_mfma_f32_16x16x32_bf16(a[i], b[j], acc[i][j], 0, 0, 0);
        }
        __syncthreads();
    }

    int m0 = tm * 64 + wm, n0 = tn * 128 + wn;
    #pragma unroll
    for (int i = 0; i < 2; i++) {
        int mm = m0 + i * 16 + q * 4;
        float rs[4];
        #pragma unroll
        for (int r = 0; r < 4; r++) rs[r] = (rowscale != nullptr) ? rowscale[mm + r] : 1.0f;
        #pragma unroll
        for (int j = 0; j < 4; j++) {
            int nn = n0 + j * 16 + r16;
            #pragma unroll
            for (int r = 0; r < 4; r++) {
                float v = acc[i][j][r] * rs[r];
                if (obf16) ((u16*)C)[coff + (long)(mm + r) * ldc + nn] = f2b(v);
                else       C[coff + (long)(mm + r) * ldc + nn] = v;
            }
        }
    }
}

// ---- GEMM 128x128, BK=128 (stage out): 2 MFMA/ds_read, 64KB LDS, 2 blocks/CU ----
__global__ __launch_bounds__(256, 2) void gemm128(
    const u16* __restrict__ A, const u16* __restrict__ B,
    float* __restrict__ C, const float* __restrict__ rowscale,
    int lda, int ldb, int ldc, int tilesN, int kIters) {
    __shared__ __align__(16) u16 As[128 * 128];   // 32 KB
    __shared__ __align__(16) u16 Bs[128 * 128];   // 32 KB
    int bid = blockIdx.x;
    int nx = gridDim.x;
    if ((nx & 7) == 0) { int cpx = nx >> 3; bid = (bid & 7) * cpx + (bid >> 3); }
    int tm = bid / tilesN, tn = bid % tilesN;
    const u16* Ap = A + (long)tm * 128 * lda;
    const u16* Bp = B + (long)tn * 128 * ldb;

    int t = threadIdx.x;
    int lane = t & 63, w = t >> 6;
    int wm = (w & 1) * 64, wn = (w >> 1) * 64;
    int r16 = lane & 15, q = lane >> 4;

    floatx4 acc[4][4];
    #pragma unroll
    for (int i = 0; i < 4; i++)
        #pragma unroll
        for (int j = 0; j < 4; j++) acc[i][j] = (floatx4){0.f, 0.f, 0.f, 0.f};

    for (int kt = 0; kt < kIters; kt++) {
        long kk = (long)kt * 128;
        #pragma unroll
        for (int j = 0; j < 8; j++) {   // 128 rows x 16 chunks = 2048
            int cl = j * 256 + t, row = cl >> 4, cg = (cl & 15) ^ (row & 15);
            gld16(Ap + (long)row * lda + kk + cg * 8, (void*)&As[cl * 8]);
        }
        #pragma unroll
        for (int j = 0; j < 8; j++) {
            int cl = j * 256 + t, row = cl >> 4, cg = (cl & 15) ^ (row & 15);
            gld16(Bp + (long)row * ldb + kk + cg * 8, (void*)&Bs[cl * 8]);
        }
        __syncthreads();
        #pragma unroll
        for (int ks = 0; ks < 4; ks++) {
            short8 a[4], b[4];
            #pragma unroll
            for (int i = 0; i < 4; i++) {
                int rr = wm + i * 16 + r16;
                int cc = (ks * 4 + q) ^ (rr & 15);
                a[i] = *(const short8*)&As[rr * 128 + cc * 8];
            }
            #pragma unroll
            for (int j = 0; j < 4; j++) {
                int rr = wn + j * 16 + r16;
                int cc = (ks * 4 + q) ^ (rr & 15);
                b[j] = *(const short8*)&Bs[rr * 128 + cc * 8];
            }
            #pragma unroll
            for (int i = 0; i < 4; i++)
                #pragma unroll
                for (int j = 0; j < 4; j++)
                    acc[i][j] = __builtin_amdgcn_mfma_f32_16x16x32_bf16(a[i], b[j], acc[i][j], 0, 0, 0);
        }
        __syncthreads();
    }

    int m0 = tm * 128 + wm, n0 = tn * 128 + wn;
    #pragma unroll
    for (int i = 0; i < 4; i++) {
        int mm = m0 + i * 16 + q * 4;
        float rs[4];
        #pragma unroll
        for (int r = 0; r < 4; r++) rs[r] = (rowscale != nullptr) ? rowscale[mm + r] : 1.0f;
        #pragma unroll
        for (int j = 0; j < 4; j++) {
            int nn = n0 + j * 16 + r16;
            #pragma unroll
            for (int r = 0; r < 4; r++)
                C[(long)(mm + r) * ldc + nn] = acc[i][j][r] * rs[r];
        }
    }
}

extern "C" void kernel_launch(void* const* d_in, const int* in_sizes, int n_in,
                              void* d_out, int out_size, void* d_ws, size_t ws_size,
                              hipStream_t stream) {
    const float* x = (const float*)d_in[0];
    const float* wgt = (const float*)d_in[1];
    float* out = (float*)d_out;
    char* ws = (char*)d_ws;

    const size_t MB = 1048576;
    u16*   YT = (u16*)ws;                  // 16 MB  Y^T = (diag(sqrt r)x)^T [1024][8192]
    u16*   Yn = (u16*)(ws + 16 * MB);      // 16 MB  diag(r)x row-major [8192][1024]
    u16*   Wt = (u16*)(ws + 32 * MB);      //  2 MB  W^T bf16
    u16*   Gb = (u16*)(ws + 34 * MB);      //  2 MB  G bf16
    u16*   Mt = (u16*)(ws + 36 * MB);      //  2 MB  M^T bf16
    float* Gp = (float*)(ws + 38 * MB);    // 32 MB  8x4MB G partials
    // total 70 MB

    // 1) fused: row norms + Y^T + Yn + W^T (blocks 0..255 / 256..511)
    prep_all<<<512, 256, 0, stream>>>(x, wgt, YT, Yn, Wt);
    // 2) G = Y^T·Y, upper-tri tiles (72 of 128 in 16x8 grid), split-K=8 -> Gp
    gemm64x128<<<dim3(72, 8), 256, 0, stream>>>(YT, YT, Gp, nullptr,
                                                8192, 8192, 1024, 8, 8, 1048576, 1, 0);
    // 3) Gb = bf16(sum Gp), mirroring the lower triangle (read-once)
    reduce_symC<<<256, 256, 0, stream>>>(Gp, Gb, 8, 1048576);
    // 4) M^T = W^T·G (G symmetric), no split-K, bf16 out -> Mt
    gemm64x128<<<dim3(128, 1), 256, 0, stream>>>(Wt, Gb, (float*)Mt, nullptr,
                                                 1024, 1024, 1024, 8, 8, 0, 0, 1);
    // 5) out = Yn·M  (M=8192, N=1024, K=1024, 512 blocks)
    gemm128<<<dim3(512, 1), 256, 0, stream>>>(Yn, Mt, out, nullptr,
                                              1024, 1024, 1024, 8, 8);
}